// Round 14
// baseline (810.938 us; speedup 1.0000x reference)
//
#include <hip/hip_runtime.h>

typedef float v2f __attribute__((ext_vector_type(2)));
typedef int   v2i __attribute__((ext_vector_type(2)));
typedef int   v8i __attribute__((ext_vector_type(8)));

#define VOCABN 5000
#define EMBD   16
#define HIDN   32
#define GATES  128   // 4*HID
#define BATCH  512
#define SEQT   2048
#define TB     8      // token batch (one s_load_dwordx8)
#define NTB    (SEQT / TB)

// Gate pre-scales folded into proj table and rec columns:
//   sigmoid(z) = 1/(1+exp2(S1*z)),  S1 = -log2(e)
//   tanh(z)    = 2/(1+exp2(S2*z))-1, S2 = -2*log2(e)
#define S1f (-1.4426950408889634f)
#define S2f (-2.8853900817779268f)

__device__ __forceinline__ float rcp1p2(float x) {   // 1/(1+2^x)
    return __builtin_amdgcn_rcpf(1.0f + __builtin_amdgcn_exp2f(x));
}

// Gate-split proj table, one v2f per (token, lane):
//   lane l<32  (j=l):    { S1*z_i[j], S2*z_g[j] }
//   lane l>=32 (j=l-32): { S1*z_f[j], S1*z_o[j] }
__global__ __launch_bounds__(64, 1) void build_proj_kernel(
    const float* __restrict__ emb, const float* __restrict__ W,
    const float* __restrict__ bias, v2f* __restrict__ proj2)
{
    const int v = blockIdx.x;
    const int l = threadIdx.x;
    const int j = l & 31;
    const int half = l >> 5;
    const int c0 = j + half * 32;        // i (lower) / f (upper)
    const int c1 = j + 64 + half * 32;   // g (lower) / o (upper)
    const float sc1 = half ? S1f : S2f;

    float e[EMBD];
#pragma unroll
    for (int k = 0; k < EMBD; ++k) e[k] = emb[v * EMBD + k];
    float z0 = bias[c0];
    float z1 = bias[c1];
#pragma unroll
    for (int k = 0; k < EMBD; ++k) {
        z0 = __builtin_fmaf(e[k], W[k * GATES + c0], z0);
        z1 = __builtin_fmaf(e[k], W[k * GATES + c1], z1);
    }
    proj2[(size_t)v * 64 + l] = (v2f){ S1f * z0, sc1 * z1 };
}

// TWO batch rows per 64-lane wave, interleaved (independent chains).
// R11 analysis: step = 531 cyc = ~190 VALU issue + ~340 exposed dep-chain
// stall, memory fully hidden, exactly 1 wave/SIMD. Row B's issue fills
// row A's stalls (ILP substitute for the TLP the problem can't provide).
// Weights R2 are shared between the rows. Per-row structure unchanged
// from R11: gate-split halves, readlane h-broadcast, pk_fma matvec,
// permlane32_swap exchange, pre-scaled exp2 activations, batched tokens.
__global__ __launch_bounds__(64, 1) void lstm_scan_kernel(
    const int* __restrict__ tokens, const float* __restrict__ rec,
    const v2f* __restrict__ proj2, float* __restrict__ out)
{
    const int bp = blockIdx.x;           // row pair
    const int b0 = bp * 2, b1 = bp * 2 + 1;
    const int l = threadIdx.x;
    const int j = l & 31;
    const int half = l >> 5;
    const int c0 = j + half * 32;
    const int c1 = j + 64 + half * 32;
    const float sc1 = half ? S1f : S2f;

    // Pre-scaled rec columns for this lane's gate pair (64 VGPRs, shared)
    v2f R2[HIDN];
#pragma unroll
    for (int k = 0; k < HIDN; ++k) {
        R2[k] = (v2f){ S1f * rec[k * GATES + c0], sc1 * rec[k * GATES + c1] };
    }

    const int* __restrict__ trowA = tokens + (size_t)b0 * SEQT;
    const int* __restrict__ trowB = tokens + (size_t)b1 * SEQT;

    float csA = 0.0f, hA = 0.0f;   // cs = S2 * c (upper half meaningful)
    float csB = 0.0f, hB = 0.0f;

    // token batches, double-buffered (uniform -> SGPRs), per row
    v8i tokA   = *(const v8i*)(trowA);
    v8i tokA_n = *(const v8i*)(trowA + TB);
    v8i tokB   = *(const v8i*)(trowB);
    v8i tokB_n = *(const v8i*)(trowB + TB);

    // xz gather pipelines, depth 2, per row
    v2f xzA0 = proj2[(size_t)tokA[0] * 64 + l];
    v2f xzB0 = proj2[(size_t)tokB[0] * 64 + l];
    v2f xzA1 = proj2[(size_t)tokA[1] * 64 + l];
    v2f xzB1 = proj2[(size_t)tokB[1] * 64 + l];

    for (int tb = 0; tb < NTB; ++tb) {
        const int nb = (tb + 2 < NTB) ? (tb + 2) : (NTB - 1);
        const v8i tokA_nn = *(const v8i*)(trowA + nb * TB);
        const v8i tokB_nn = *(const v8i*)(trowB + nb * TB);

#pragma unroll
        for (int s = 0; s < TB; ++s) {
            const int tpA = (s < TB - 2) ? tokA[s + 2] : tokA_n[s - (TB - 2)];
            const int tpB = (s < TB - 2) ? tokB[s + 2] : tokB_n[s - (TB - 2)];
            const v2f xzA2 = proj2[(size_t)tpA * 64 + l];
            const v2f xzB2 = proj2[(size_t)tpB * 64 + l];

            // ---- matvecs (independent; compiler interleaves) ----
            v2f aA0 = xzA0, aA1 = (v2f){0.f,0.f}, aA2 = (v2f){0.f,0.f}, aA3 = (v2f){0.f,0.f};
            v2f aB0 = xzB0, aB1 = (v2f){0.f,0.f}, aB2 = (v2f){0.f,0.f}, aB3 = (v2f){0.f,0.f};
#pragma unroll
            for (int k = 0; k < HIDN; k += 4) {
                const float hA0 = __int_as_float(__builtin_amdgcn_readlane(__float_as_int(hA), 32 + k));
                const float hA1 = __int_as_float(__builtin_amdgcn_readlane(__float_as_int(hA), 32 + k + 1));
                const float hA2 = __int_as_float(__builtin_amdgcn_readlane(__float_as_int(hA), 32 + k + 2));
                const float hA3 = __int_as_float(__builtin_amdgcn_readlane(__float_as_int(hA), 32 + k + 3));
                aA0 = __builtin_elementwise_fma((v2f){hA0, hA0}, R2[k],     aA0);
                aA1 = __builtin_elementwise_fma((v2f){hA1, hA1}, R2[k + 1], aA1);
                aA2 = __builtin_elementwise_fma((v2f){hA2, hA2}, R2[k + 2], aA2);
                aA3 = __builtin_elementwise_fma((v2f){hA3, hA3}, R2[k + 3], aA3);
                const float hB0 = __int_as_float(__builtin_amdgcn_readlane(__float_as_int(hB), 32 + k));
                const float hB1 = __int_as_float(__builtin_amdgcn_readlane(__float_as_int(hB), 32 + k + 1));
                const float hB2 = __int_as_float(__builtin_amdgcn_readlane(__float_as_int(hB), 32 + k + 2));
                const float hB3 = __int_as_float(__builtin_amdgcn_readlane(__float_as_int(hB), 32 + k + 3));
                aB0 = __builtin_elementwise_fma((v2f){hB0, hB0}, R2[k],     aB0);
                aB1 = __builtin_elementwise_fma((v2f){hB1, hB1}, R2[k + 1], aB1);
                aB2 = __builtin_elementwise_fma((v2f){hB2, hB2}, R2[k + 2], aB2);
                aB3 = __builtin_elementwise_fma((v2f){hB3, hB3}, R2[k + 3], aB3);
            }
            const v2f zA = (aA0 + aA1) + (aA2 + aA3);
            const v2f zB = (aB0 + aB1) + (aB2 + aB3);

            // ---- activations row A ----
            const float uA = rcp1p2(zA.x);
            const float wA = rcp1p2(zA.y);
            const float ggA = __builtin_fmaf(2.0f, wA, -1.0f);
            const float pA = (S2f * uA) * ggA;
            const v2i prA = __builtin_amdgcn_permlane32_swap(
                __float_as_int(pA), __float_as_int(pA), false, false);
            const float psA = __int_as_float(prA[0]);
            const float cnsA = __builtin_fmaf(uA, csA, psA);
            const float tcA = __builtin_fmaf(2.0f, rcp1p2(cnsA), -1.0f);
            const float hnA = wA * tcA;

            // ---- activations row B ----
            const float uB = rcp1p2(zB.x);
            const float wB = rcp1p2(zB.y);
            const float ggB = __builtin_fmaf(2.0f, wB, -1.0f);
            const float pB = (S2f * uB) * ggB;
            const v2i prB = __builtin_amdgcn_permlane32_swap(
                __float_as_int(pB), __float_as_int(pB), false, false);
            const float psB = __int_as_float(prB[0]);
            const float cnsB = __builtin_fmaf(uB, csB, psB);
            const float tcB = __builtin_fmaf(2.0f, rcp1p2(cnsB), -1.0f);
            const float hnB = wB * tcB;

            const bool mA = (tokA[s] != 0);
            const bool mB = (tokB[s] != 0);
            csA = mA ? cnsA : csA;
            hA  = mA ? hnA  : hA;
            csB = mB ? cnsB : csB;
            hB  = mB ? hnB  : hB;

            xzA0 = xzA1; xzA1 = xzA2;
            xzB0 = xzB1; xzB1 = xzB2;
        }

        tokA = tokA_n; tokA_n = tokA_nn;
        tokB = tokB_n; tokB_n = tokB_nn;
    }

    if (half) {
        out[(size_t)b0 * HIDN + j] = hA;
        out[(size_t)b1 * HIDN + j] = hB;
    }
}

extern "C" void kernel_launch(void* const* d_in, const int* in_sizes, int n_in,
                              void* d_out, int out_size, void* d_ws, size_t ws_size,
                              hipStream_t stream)
{
    const int*   tokens = (const int*)d_in[0];
    const float* emb    = (const float*)d_in[1];
    const float* W      = (const float*)d_in[2];
    const float* rec    = (const float*)d_in[3];
    const float* bias   = (const float*)d_in[4];
    float* out = (float*)d_out;
    v2f* proj2 = (v2f*)d_ws;   // VOCABN*64 v2f = 2.56 MB

    hipLaunchKernelGGL(build_proj_kernel, dim3(VOCABN), dim3(64), 0, stream,
                       emb, W, bias, proj2);
    hipLaunchKernelGGL(lstm_scan_kernel, dim3(BATCH / 2), dim3(64), 0, stream,
                       tokens, rec, proj2, out);
}

// Round 15
// 779.341 us; speedup vs baseline: 1.0405x; 1.0405x over previous
//
#include <hip/hip_runtime.h>

typedef float v2f __attribute__((ext_vector_type(2)));
typedef int   v2i __attribute__((ext_vector_type(2)));
typedef int   v8i __attribute__((ext_vector_type(8)));

#define VOCABN 5000
#define EMBD   16
#define HIDN   32
#define GATES  128   // 4*HID
#define BATCH  512
#define SEQT   2048
#define TB     8      // token batch (one s_load_dwordx8)
#define NTB    (SEQT / TB)

// Gate pre-scales folded into proj table and rec columns:
//   sigmoid(z) = 1/(1+exp2(S1*z)),  S1 = -log2(e)
//   tanh(z)    = 2/(1+exp2(S2*z))-1, S2 = -2*log2(e)
#define S1f (-1.4426950408889634f)
#define S2f (-2.8853900817779268f)

__device__ __forceinline__ float rcp1p2(float x) {   // 1/(1+2^x)
    return __builtin_amdgcn_rcpf(1.0f + __builtin_amdgcn_exp2f(x));
}

// Gate-split proj table, one v2f per (token, lane):
//   lane l<32  (j=l):    { S1*z_i[j], S2*z_g[j] }
//   lane l>=32 (j=l-32): { S1*z_f[j], S1*z_o[j] }
__global__ __launch_bounds__(64, 1) void build_proj_kernel(
    const float* __restrict__ emb, const float* __restrict__ W,
    const float* __restrict__ bias, v2f* __restrict__ proj2)
{
    const int v = blockIdx.x;
    const int l = threadIdx.x;
    const int j = l & 31;
    const int half = l >> 5;
    const int c0 = j + half * 32;        // i (lower) / f (upper)
    const int c1 = j + 64 + half * 32;   // g (lower) / o (upper)
    const float sc1 = half ? S1f : S2f;

    float e[EMBD];
#pragma unroll
    for (int k = 0; k < EMBD; ++k) e[k] = emb[v * EMBD + k];
    float z0 = bias[c0];
    float z1 = bias[c1];
#pragma unroll
    for (int k = 0; k < EMBD; ++k) {
        z0 = __builtin_fmaf(e[k], W[k * GATES + c0], z0);
        z1 = __builtin_fmaf(e[k], W[k * GATES + c1], z1);
    }
    proj2[(size_t)v * 64 + l] = (v2f){ S1f * z0, sc1 * z1 };
}

// TWO batch rows per 64-lane wave (R12 structure), with the activation
// chains of the two rows HAND-INTERLEAVED instruction-by-instruction.
// R12 post-mortem: pair-step 955 cyc ~= 2x531 because act-A block then
// act-B block serialized on the in-order wave: B's independent trans ops
// sat after A's serial exp2->add->rcp chain in program order. The wave
// can only overlap latencies of instructions that ALTERNATE in program
// order; the compiler preserves source order around trans/convergent ops.
__global__ __launch_bounds__(64, 1) void lstm_scan_kernel(
    const int* __restrict__ tokens, const float* __restrict__ rec,
    const v2f* __restrict__ proj2, float* __restrict__ out)
{
    const int bp = blockIdx.x;           // row pair
    const int b0 = bp * 2, b1 = bp * 2 + 1;
    const int l = threadIdx.x;
    const int j = l & 31;
    const int half = l >> 5;
    const int c0 = j + half * 32;
    const int c1 = j + 64 + half * 32;
    const float sc1 = half ? S1f : S2f;

    // Pre-scaled rec columns for this lane's gate pair (64 VGPRs, shared)
    v2f R2[HIDN];
#pragma unroll
    for (int k = 0; k < HIDN; ++k) {
        R2[k] = (v2f){ S1f * rec[k * GATES + c0], sc1 * rec[k * GATES + c1] };
    }

    const int* __restrict__ trowA = tokens + (size_t)b0 * SEQT;
    const int* __restrict__ trowB = tokens + (size_t)b1 * SEQT;

    float csA = 0.0f, hA = 0.0f;   // cs = S2 * c (upper half meaningful)
    float csB = 0.0f, hB = 0.0f;

    v8i tokA   = *(const v8i*)(trowA);
    v8i tokA_n = *(const v8i*)(trowA + TB);
    v8i tokB   = *(const v8i*)(trowB);
    v8i tokB_n = *(const v8i*)(trowB + TB);

    v2f xzA0 = proj2[(size_t)tokA[0] * 64 + l];
    v2f xzB0 = proj2[(size_t)tokB[0] * 64 + l];
    v2f xzA1 = proj2[(size_t)tokA[1] * 64 + l];
    v2f xzB1 = proj2[(size_t)tokB[1] * 64 + l];

    for (int tb = 0; tb < NTB; ++tb) {
        const int nb = (tb + 2 < NTB) ? (tb + 2) : (NTB - 1);
        const v8i tokA_nn = *(const v8i*)(trowA + nb * TB);
        const v8i tokB_nn = *(const v8i*)(trowB + nb * TB);

#pragma unroll
        for (int s = 0; s < TB; ++s) {
            const int tpA = (s < TB - 2) ? tokA[s + 2] : tokA_n[s - (TB - 2)];
            const int tpB = (s < TB - 2) ? tokB[s + 2] : tokB_n[s - (TB - 2)];
            const v2f xzA2 = proj2[(size_t)tpA * 64 + l];
            const v2f xzB2 = proj2[(size_t)tpB * 64 + l];

            // ---- matvecs, A/B interleaved per k-group ----
            v2f aA0 = xzA0, aA1 = (v2f){0.f,0.f}, aA2 = (v2f){0.f,0.f}, aA3 = (v2f){0.f,0.f};
            v2f aB0 = xzB0, aB1 = (v2f){0.f,0.f}, aB2 = (v2f){0.f,0.f}, aB3 = (v2f){0.f,0.f};
#pragma unroll
            for (int k = 0; k < HIDN; k += 4) {
                const float hA0 = __int_as_float(__builtin_amdgcn_readlane(__float_as_int(hA), 32 + k));
                const float hB0 = __int_as_float(__builtin_amdgcn_readlane(__float_as_int(hB), 32 + k));
                const float hA1 = __int_as_float(__builtin_amdgcn_readlane(__float_as_int(hA), 32 + k + 1));
                const float hB1 = __int_as_float(__builtin_amdgcn_readlane(__float_as_int(hB), 32 + k + 1));
                const float hA2 = __int_as_float(__builtin_amdgcn_readlane(__float_as_int(hA), 32 + k + 2));
                const float hB2 = __int_as_float(__builtin_amdgcn_readlane(__float_as_int(hB), 32 + k + 2));
                const float hA3 = __int_as_float(__builtin_amdgcn_readlane(__float_as_int(hA), 32 + k + 3));
                const float hB3 = __int_as_float(__builtin_amdgcn_readlane(__float_as_int(hB), 32 + k + 3));
                aA0 = __builtin_elementwise_fma((v2f){hA0, hA0}, R2[k],     aA0);
                aB0 = __builtin_elementwise_fma((v2f){hB0, hB0}, R2[k],     aB0);
                aA1 = __builtin_elementwise_fma((v2f){hA1, hA1}, R2[k + 1], aA1);
                aB1 = __builtin_elementwise_fma((v2f){hB1, hB1}, R2[k + 1], aB1);
                aA2 = __builtin_elementwise_fma((v2f){hA2, hA2}, R2[k + 2], aA2);
                aB2 = __builtin_elementwise_fma((v2f){hB2, hB2}, R2[k + 2], aB2);
                aA3 = __builtin_elementwise_fma((v2f){hA3, hA3}, R2[k + 3], aA3);
                aB3 = __builtin_elementwise_fma((v2f){hB3, hB3}, R2[k + 3], aB3);
            }
            // z reductions, interleaved
            const v2f zAu = aA0 + aA1;
            const v2f zBu = aB0 + aB1;
            const v2f zAv = aA2 + aA3;
            const v2f zBv = aB2 + aB3;
            const v2f zA = zAu + zAv;
            const v2f zB = zBu + zBv;

            // ---- activations, A/B interleaved instruction-by-instruction ----
            const float eiA = __builtin_amdgcn_exp2f(zA.x);
            const float eiB = __builtin_amdgcn_exp2f(zB.x);
            const float egA = __builtin_amdgcn_exp2f(zA.y);
            const float egB = __builtin_amdgcn_exp2f(zB.y);
            const float uA = __builtin_amdgcn_rcpf(1.0f + eiA);   // ig / fg
            const float uB = __builtin_amdgcn_rcpf(1.0f + eiB);
            const float wA = __builtin_amdgcn_rcpf(1.0f + egA);   // gg' / og
            const float wB = __builtin_amdgcn_rcpf(1.0f + egB);
            // p = u * (2*S2*w - S2)  == S2 * ig * tanh(zg)   (one less serial mul)
            const float pA = uA * __builtin_fmaf(2.0f * S2f, wA, -S2f);
            const float pB = uB * __builtin_fmaf(2.0f * S2f, wB, -S2f);
            const v2i prA = __builtin_amdgcn_permlane32_swap(
                __float_as_int(pA), __float_as_int(pA), false, false);
            const v2i prB = __builtin_amdgcn_permlane32_swap(
                __float_as_int(pB), __float_as_int(pB), false, false);
            const float psA = __int_as_float(prA[0]);
            const float psB = __int_as_float(prB[0]);
            const float cnsA = __builtin_fmaf(uA, csA, psA);      // S2*(fg*c+ig*gg)
            const float cnsB = __builtin_fmaf(uB, csB, psB);
            const float ecA = __builtin_amdgcn_exp2f(cnsA);
            const float ecB = __builtin_amdgcn_exp2f(cnsB);
            const float rcA = __builtin_amdgcn_rcpf(1.0f + ecA);
            const float rcB = __builtin_amdgcn_rcpf(1.0f + ecB);
            const float hnA = wA * __builtin_fmaf(2.0f, rcA, -1.0f);
            const float hnB = wB * __builtin_fmaf(2.0f, rcB, -1.0f);

            const bool mA = (tokA[s] != 0);
            const bool mB = (tokB[s] != 0);
            csA = mA ? cnsA : csA;
            csB = mB ? cnsB : csB;
            hA  = mA ? hnA  : hA;
            hB  = mB ? hnB  : hB;

            xzA0 = xzA1; xzA1 = xzA2;
            xzB0 = xzB1; xzB1 = xzB2;
        }

        tokA = tokA_n; tokA_n = tokA_nn;
        tokB = tokB_n; tokB_n = tokB_nn;
    }

    if (half) {
        out[(size_t)b0 * HIDN + j] = hA;
        out[(size_t)b1 * HIDN + j] = hB;
    }
}

extern "C" void kernel_launch(void* const* d_in, const int* in_sizes, int n_in,
                              void* d_out, int out_size, void* d_ws, size_t ws_size,
                              hipStream_t stream)
{
    const int*   tokens = (const int*)d_in[0];
    const float* emb    = (const float*)d_in[1];
    const float* W      = (const float*)d_in[2];
    const float* rec    = (const float*)d_in[3];
    const float* bias   = (const float*)d_in[4];
    float* out = (float*)d_out;
    v2f* proj2 = (v2f*)d_ws;   // VOCABN*64 v2f = 2.56 MB

    hipLaunchKernelGGL(build_proj_kernel, dim3(VOCABN), dim3(64), 0, stream,
                       emb, W, bias, proj2);
    hipLaunchKernelGGL(lstm_scan_kernel, dim3(BATCH / 2), dim3(64), 0, stream,
                       tokens, rec, proj2, out);
}

// Round 17
// 693.991 us; speedup vs baseline: 1.1685x; 1.1230x over previous
//
#include <hip/hip_runtime.h>

typedef float v2f __attribute__((ext_vector_type(2)));
typedef int   v2i __attribute__((ext_vector_type(2)));
typedef int   v8i __attribute__((ext_vector_type(8)));

#define VOCABN 5000
#define EMBD   16
#define HIDN   32
#define GATES  128   // 4*HID
#define BATCH  512
#define SEQT   2048
#define TB     8      // token batch (one s_load_dwordx8)
#define NTB    (SEQT / TB)

// Gate pre-scales folded into proj table and rec columns:
//   sigmoid(z) = 1/(1+exp2(S1*z)),  S1 = -log2(e)
//   tanh(z)    = 2/(1+exp2(S2*z))-1, S2 = -2*log2(e)
#define S1f (-1.4426950408889634f)
#define S2f (-2.8853900817779268f)

// Gate-split proj table, one v2f per (token, lane):
//   lane l<32  (j=l):    { S1*z_i[j], S2*z_g[j] }
//   lane l>=32 (j=l-32): { S1*z_f[j], S1*z_o[j] }
__global__ __launch_bounds__(64, 1) void build_proj_kernel(
    const float* __restrict__ emb, const float* __restrict__ W,
    const float* __restrict__ bias, v2f* __restrict__ proj2)
{
    const int v = blockIdx.x;
    const int l = threadIdx.x;
    const int j = l & 31;
    const int half = l >> 5;
    const int c0 = j + half * 32;        // i (lower) / f (upper)
    const int c1 = j + 64 + half * 32;   // g (lower) / o (upper)
    const float sc1 = half ? S1f : S2f;

    float e[EMBD];
#pragma unroll
    for (int k = 0; k < EMBD; ++k) e[k] = emb[v * EMBD + k];
    float z0 = bias[c0];
    float z1 = bias[c1];
#pragma unroll
    for (int k = 0; k < EMBD; ++k) {
        z0 = __builtin_fmaf(e[k], W[k * GATES + c0], z0);
        z1 = __builtin_fmaf(e[k], W[k * GATES + c1], z1);
    }
    proj2[(size_t)v * 64 + l] = (v2f){ S1f * z0, sc1 * z1 };
}

// TWO rows per wave, SECTIONED software pipeline. R13 analysis: issue-bound
// (82% busy), ~190 instr/row-step, of which the h-broadcast (32 readlane +
// 32 splat movs) is ~128 cyc. This version broadcasts h through LDS instead:
// 1 ds_write + 16 same-address v2f reads (broadcast, conflict-free), feeding
// v_pk_fma over {k,k+1} pairs -> no readlanes, no splats (~75 instr/row).
// The ~150cy LDS write->read latency is hidden by section order:
//   ... fmaA(t) actA writeA readA(t+1) | fmaB(t) actB writeB readB(t+1) | ...
// each row's read-to-use gap is the other row's full section.
__global__ __launch_bounds__(64, 1) void lstm_scan_kernel(
    const int* __restrict__ tokens, const float* __restrict__ rec,
    const v2f* __restrict__ proj2, float* __restrict__ out)
{
    const int bp = blockIdx.x;           // row pair
    const int b0 = bp * 2, b1 = bp * 2 + 1;
    const int l = threadIdx.x;
    const int j = l & 31;
    const int half = l >> 5;
    const int c0 = j + half * 32;
    const int c1 = j + 64 + half * 32;
    const float sc1 = half ? S1f : S2f;

    // rec columns k-pair-packed per gate: Rc0[p]={R[2p][c0],R[2p+1][c0]} etc.
    v2f Rc0[16], Rc1[16];
#pragma unroll
    for (int p = 0; p < 16; ++p) {
        Rc0[p] = (v2f){ S1f * rec[(2 * p) * GATES + c0], S1f * rec[(2 * p + 1) * GATES + c0] };
        Rc1[p] = (v2f){ sc1 * rec[(2 * p) * GATES + c1], sc1 * rec[(2 * p + 1) * GATES + c1] };
    }

    __shared__ float hsA[64], hsB[64];
    hsA[l] = 0.0f;
    hsB[l] = 0.0f;

    const int* __restrict__ trowA = tokens + (size_t)b0 * SEQT;
    const int* __restrict__ trowB = tokens + (size_t)b1 * SEQT;

    float csA = 0.0f, hA = 0.0f;   // cs = S2*c; h meaningful in upper lanes
    float csB = 0.0f, hB = 0.0f;

    v8i tokA   = *(const v8i*)(trowA);
    v8i tokA_n = *(const v8i*)(trowA + TB);
    v8i tokB   = *(const v8i*)(trowB);
    v8i tokB_n = *(const v8i*)(trowB + TB);

    v2f xzA0 = proj2[(size_t)tokA[0] * 64 + l];
    v2f xzB0 = proj2[(size_t)tokB[0] * 64 + l];
    v2f xzA1 = proj2[(size_t)tokA[1] * 64 + l];
    v2f xzB1 = proj2[(size_t)tokB[1] * 64 + l];

    // broadcast-read pointers (same address for all lanes -> LDS broadcast)
    const v2f* hpA = (const v2f*)(&hsA[32]);
    const v2f* hpB = (const v2f*)(&hsB[32]);

    // initial h (zeros) into registers
    v2f hrA[16], hrB[16];
#pragma unroll
    for (int p = 0; p < 16; ++p) { hrA[p] = hpA[p]; hrB[p] = hpB[p]; }

    for (int tb = 0; tb < NTB; ++tb) {
        const int nb = (tb + 2 < NTB) ? (tb + 2) : (NTB - 1);
        const v8i tokA_nn = *(const v8i*)(trowA + nb * TB);
        const v8i tokB_nn = *(const v8i*)(trowB + nb * TB);

#pragma unroll
        for (int s = 0; s < TB; ++s) {
            const int tpA = (s < TB - 2) ? tokA[s + 2] : tokA_n[s - (TB - 2)];
            const int tpB = (s < TB - 2) ? tokB[s + 2] : tokB_n[s - (TB - 2)];

            // ================= A section =================
            const v2f xzA2 = proj2[(size_t)tpA * 64 + l];
            {
                v2f a0 = (v2f){0.f, 0.f}, a1 = (v2f){0.f, 0.f};
                v2f g0 = (v2f){0.f, 0.f}, g1 = (v2f){0.f, 0.f};
#pragma unroll
                for (int p = 0; p < 16; p += 2) {
                    a0 = __builtin_elementwise_fma(hrA[p],     Rc0[p],     a0);
                    g0 = __builtin_elementwise_fma(hrA[p],     Rc1[p],     g0);
                    a1 = __builtin_elementwise_fma(hrA[p + 1], Rc0[p + 1], a1);
                    g1 = __builtin_elementwise_fma(hrA[p + 1], Rc1[p + 1], g1);
                }
                const v2f sa = a0 + a1;
                const v2f sg = g0 + g1;
                const float z0 = (sa.x + sa.y) + xzA0.x;
                const float z1 = (sg.x + sg.y) + xzA0.y;

                const float ei = __builtin_amdgcn_exp2f(z0);
                const float eg = __builtin_amdgcn_exp2f(z1);
                const float u = __builtin_amdgcn_rcpf(1.0f + ei);   // ig / fg
                const float w = __builtin_amdgcn_rcpf(1.0f + eg);   // gg' / og
                const float p = u * __builtin_fmaf(2.0f * S2f, w, -S2f); // S2*ig*gg
                const v2i pr = __builtin_amdgcn_permlane32_swap(
                    __float_as_int(p), __float_as_int(p), false, false);
                const float ps = __int_as_float(pr[0]);
                const float cns = __builtin_fmaf(u, csA, ps);       // S2*c_new
                const float ec = __builtin_amdgcn_exp2f(cns);
                const float rc = __builtin_amdgcn_rcpf(1.0f + ec);
                const float hn = w * __builtin_fmaf(2.0f, rc, -1.0f);

                const bool m = (tokA[s] != 0);
                csA = m ? cns : csA;
                hA  = m ? hn : hA;
            }
            hsA[l] = hA;                        // publish h_t
#pragma unroll
            for (int p = 0; p < 16; ++p) hrA[p] = hpA[p];   // read for t+1
            xzA0 = xzA1; xzA1 = xzA2;

            // ================= B section =================
            const v2f xzB2 = proj2[(size_t)tpB * 64 + l];
            {
                v2f a0 = (v2f){0.f, 0.f}, a1 = (v2f){0.f, 0.f};
                v2f g0 = (v2f){0.f, 0.f}, g1 = (v2f){0.f, 0.f};
#pragma unroll
                for (int p = 0; p < 16; p += 2) {
                    a0 = __builtin_elementwise_fma(hrB[p],     Rc0[p],     a0);
                    g0 = __builtin_elementwise_fma(hrB[p],     Rc1[p],     g0);
                    a1 = __builtin_elementwise_fma(hrB[p + 1], Rc0[p + 1], a1);
                    g1 = __builtin_elementwise_fma(hrB[p + 1], Rc1[p + 1], g1);
                }
                const v2f sa = a0 + a1;
                const v2f sg = g0 + g1;
                const float z0 = (sa.x + sa.y) + xzB0.x;
                const float z1 = (sg.x + sg.y) + xzB0.y;

                const float ei = __builtin_amdgcn_exp2f(z0);
                const float eg = __builtin_amdgcn_exp2f(z1);
                const float u = __builtin_amdgcn_rcpf(1.0f + ei);
                const float w = __builtin_amdgcn_rcpf(1.0f + eg);
                const float p = u * __builtin_fmaf(2.0f * S2f, w, -S2f);
                const v2i pr = __builtin_amdgcn_permlane32_swap(
                    __float_as_int(p), __float_as_int(p), false, false);
                const float ps = __int_as_float(pr[0]);
                const float cns = __builtin_fmaf(u, csB, ps);
                const float ec = __builtin_amdgcn_exp2f(cns);
                const float rc = __builtin_amdgcn_rcpf(1.0f + ec);
                const float hn = w * __builtin_fmaf(2.0f, rc, -1.0f);

                const bool m = (tokB[s] != 0);
                csB = m ? cns : csB;
                hB  = m ? hn : hB;
            }
            hsB[l] = hB;
#pragma unroll
            for (int p = 0; p < 16; ++p) hrB[p] = hpB[p];
            xzB0 = xzB1; xzB1 = xzB2;
        }

        tokA = tokA_n; tokA_n = tokA_nn;
        tokB = tokB_n; tokB_n = tokB_nn;
    }

    if (half) {
        out[(size_t)b0 * HIDN + j] = hA;
        out[(size_t)b1 * HIDN + j] = hB;
    }
}

extern "C" void kernel_launch(void* const* d_in, const int* in_sizes, int n_in,
                              void* d_out, int out_size, void* d_ws, size_t ws_size,
                              hipStream_t stream)
{
    const int*   tokens = (const int*)d_in[0];
    const float* emb    = (const float*)d_in[1];
    const float* W      = (const float*)d_in[2];
    const float* rec    = (const float*)d_in[3];
    const float* bias   = (const float*)d_in[4];
    float* out = (float*)d_out;
    v2f* proj2 = (v2f*)d_ws;   // VOCABN*64 v2f = 2.56 MB

    hipLaunchKernelGGL(build_proj_kernel, dim3(VOCABN), dim3(64), 0, stream,
                       emb, W, bias, proj2);
    hipLaunchKernelGGL(lstm_scan_kernel, dim3(BATCH / 2), dim3(64), 0, stream,
                       tokens, rec, proj2, out);
}

// Round 20
// 590.878 us; speedup vs baseline: 1.3724x; 1.1745x over previous
//
#include <hip/hip_runtime.h>

typedef float v2f __attribute__((ext_vector_type(2)));
typedef int   v2i __attribute__((ext_vector_type(2)));
typedef int   v8i __attribute__((ext_vector_type(8)));

#define VOCABN 5000
#define EMBD   16
#define HIDN   32
#define GATES  128   // 4*HID
#define BATCH  512
#define SEQT   2048
#define TB     8      // token batch (one s_load_dwordx8)
#define NTB    (SEQT / TB)

// Gate pre-scales folded into proj table and rec columns:
//   sigmoid(z) = 1/(1+exp2(S1*z)),  S1 = -log2(e)
//   tanh(z)    = 2/(1+exp2(S2*z))-1, S2 = -2*log2(e)
#define S1f (-1.4426950408889634f)
#define S2f (-2.8853900817779268f)

// Gate-split proj table, one v2f per (token, lane):
//   lane l<32  (j=l):    { S1*z_i[j], S2*z_g[j] }
//   lane l>=32 (j=l-32): { S1*z_f[j], S1*z_o[j] }
__global__ __launch_bounds__(64, 1) void build_proj_kernel(
    const float* __restrict__ emb, const float* __restrict__ W,
    const float* __restrict__ bias, v2f* __restrict__ proj2)
{
    const int v = blockIdx.x;
    const int l = threadIdx.x;
    const int j = l & 31;
    const int half = l >> 5;
    const int c0 = j + half * 32;        // i (lower) / f (upper)
    const int c1 = j + 64 + half * 32;   // g (lower) / o (upper)
    const float sc1 = half ? S1f : S2f;

    float e[EMBD];
#pragma unroll
    for (int k = 0; k < EMBD; ++k) e[k] = emb[v * EMBD + k];
    float z0 = bias[c0];
    float z1 = bias[c1];
#pragma unroll
    for (int k = 0; k < EMBD; ++k) {
        z0 = __builtin_fmaf(e[k], W[k * GATES + c0], z0);
        z1 = __builtin_fmaf(e[k], W[k * GATES + c1], z1);
    }
    proj2[(size_t)v * 64 + l] = (v2f){ S1f * z0, sc1 * z1 };
}

// ONE row per wave (back to R11 structure: 512 waves on 1024 SIMDs; 2-row
// variants are arithmetically doomed at 28% stall). Matvec uses SCALAR
// v_fma_f32 with the readlane SGPR as a direct operand: per k = 1 readlane
// + 2 fma, NO {hk,hk} splat movs (R11's pk_fma forced ~64 v_movs/step —
// the hidden cost that made pk no faster than scalar). 8 split accumulators
// (4 per column) keep FMA dep-chain tails at ~32 cy.
__global__ __launch_bounds__(64, 1) void lstm_scan_kernel(
    const int* __restrict__ tokens, const float* __restrict__ rec,
    const v2f* __restrict__ proj2, float* __restrict__ out)
{
    const int b = blockIdx.x;
    const int l = threadIdx.x;
    const int j = l & 31;
    const int half = l >> 5;
    const int c0 = j + half * 32;
    const int c1 = j + 64 + half * 32;
    const float sc1 = half ? S1f : S2f;

    // Pre-scaled rec columns for this lane's two gates (64 VGPRs)
    float R0[HIDN], R1[HIDN];
#pragma unroll
    for (int k = 0; k < HIDN; ++k) {
        R0[k] = S1f * rec[k * GATES + c0];
        R1[k] = sc1 * rec[k * GATES + c1];
    }

    const int* __restrict__ trow = tokens + (size_t)b * SEQT;

    float cs = 0.0f, hval = 0.0f;   // cs = S2*c (upper half meaningful)

    v8i tokb   = *(const v8i*)(trow);
    v8i tokb_n = *(const v8i*)(trow + TB);

    v2f xz0 = proj2[(size_t)tokb[0] * 64 + l];
    v2f xz1 = proj2[(size_t)tokb[1] * 64 + l];

    for (int tb = 0; tb < NTB; ++tb) {
        const int nb = (tb + 2 < NTB) ? (tb + 2) : (NTB - 1);
        const v8i tokb_nn = *(const v8i*)(trow + nb * TB);

#pragma unroll
        for (int s = 0; s < TB; ++s) {
            const int tpre2 = (s < TB - 2) ? tokb[s + 2] : tokb_n[s - (TB - 2)];
            const v2f xz2 = proj2[(size_t)tpre2 * 64 + l];

            // z = xz + h @ rec; scalar fma with SGPR h, 4 accs per column
            float z00 = xz0.x, z01 = 0.f, z02 = 0.f, z03 = 0.f;
            float z10 = xz0.y, z11 = 0.f, z12 = 0.f, z13 = 0.f;
#pragma unroll
            for (int k = 0; k < HIDN; k += 4) {
                const float h0 = __int_as_float(
                    __builtin_amdgcn_readlane(__float_as_int(hval), 32 + k));
                const float h1 = __int_as_float(
                    __builtin_amdgcn_readlane(__float_as_int(hval), 32 + k + 1));
                const float h2 = __int_as_float(
                    __builtin_amdgcn_readlane(__float_as_int(hval), 32 + k + 2));
                const float h3 = __int_as_float(
                    __builtin_amdgcn_readlane(__float_as_int(hval), 32 + k + 3));
                z00 = __builtin_fmaf(h0, R0[k],     z00);
                z10 = __builtin_fmaf(h0, R1[k],     z10);
                z01 = __builtin_fmaf(h1, R0[k + 1], z01);
                z11 = __builtin_fmaf(h1, R1[k + 1], z11);
                z02 = __builtin_fmaf(h2, R0[k + 2], z02);
                z12 = __builtin_fmaf(h2, R1[k + 2], z12);
                z03 = __builtin_fmaf(h3, R0[k + 3], z03);
                z13 = __builtin_fmaf(h3, R1[k + 3], z13);
            }
            const float z0 = (z00 + z01) + (z02 + z03);
            const float z1 = (z10 + z11) + (z12 + z13);

            // activations (shared stream, per-half meaning)
            const float u = __builtin_amdgcn_rcpf(1.0f + __builtin_amdgcn_exp2f(z0)); // ig/fg
            const float w = __builtin_amdgcn_rcpf(1.0f + __builtin_amdgcn_exp2f(z1)); // gg'/og
            const float p = u * __builtin_fmaf(2.0f * S2f, w, -S2f);  // S2*ig*gg
            const v2i pr = __builtin_amdgcn_permlane32_swap(
                __float_as_int(p), __float_as_int(p), false, false);
            const float ps = __int_as_float(pr[0]);
            const float cns = __builtin_fmaf(u, cs, ps);              // S2*c_new
            const float rc = __builtin_amdgcn_rcpf(1.0f + __builtin_amdgcn_exp2f(cns));
            const float hn = w * __builtin_fmaf(2.0f, rc, -1.0f);     // og*tanh(cn)

            const bool m = (tokb[s] != 0);   // wave-uniform
            cs   = m ? cns : cs;
            hval = m ? hn : hval;

            xz0 = xz1; xz1 = xz2;
        }

        tokb = tokb_n;
        tokb_n = tokb_nn;
    }

    if (half) out[(size_t)b * HIDN + j] = hval;
}

extern "C" void kernel_launch(void* const* d_in, const int* in_sizes, int n_in,
                              void* d_out, int out_size, void* d_ws, size_t ws_size,
                              hipStream_t stream)
{
    const int*   tokens = (const int*)d_in[0];
    const float* emb    = (const float*)d_in[1];
    const float* W      = (const float*)d_in[2];
    const float* rec    = (const float*)d_in[3];
    const float* bias   = (const float*)d_in[4];
    float* out = (float*)d_out;
    v2f* proj2 = (v2f*)d_ws;   // VOCABN*64 v2f = 2.56 MB

    hipLaunchKernelGGL(build_proj_kernel, dim3(VOCABN), dim3(64), 0, stream,
                       emb, W, bias, proj2);
    hipLaunchKernelGGL(lstm_scan_kernel, dim3(BATCH), dim3(64), 0, stream,
                       tokens, rec, proj2, out);
}

// Round 21
// 540.515 us; speedup vs baseline: 1.5003x; 1.0932x over previous
//
#include <hip/hip_runtime.h>

typedef float v2f __attribute__((ext_vector_type(2)));
typedef int   v2i __attribute__((ext_vector_type(2)));
typedef int   v8i __attribute__((ext_vector_type(8)));

#define VOCABN 5000
#define EMBD   16
#define HIDN   32
#define GATES  128   // 4*HID
#define BATCH  512
#define SEQT   2048
#define TB     8      // token batch (one s_load_dwordx8)
#define NTB    (SEQT / TB)

// Gate pre-scales folded into proj table and rec columns:
//   sigmoid(z) = 1/(1+exp2(S1*z)),  S1 = -log2(e)
//   tanh(z)    = 2/(1+exp2(S2*z))-1, S2 = -2*log2(e)
#define S1f (-1.4426950408889634f)
#define S2f (-2.8853900817779268f)

#define RL(x, n) __int_as_float(__builtin_amdgcn_readlane(__float_as_int(x), (n)))

// Gate-split proj table, one v2f per (token, lane):
//   lane l<32  (j=l):    { S1*z_i[j], S2*z_g[j] }
//   lane l>=32 (j=l-32): { S1*z_f[j], S1*z_o[j] }
__global__ __launch_bounds__(64, 1) void build_proj_kernel(
    const float* __restrict__ emb, const float* __restrict__ W,
    const float* __restrict__ bias, v2f* __restrict__ proj2)
{
    const int v = blockIdx.x;
    const int l = threadIdx.x;
    const int j = l & 31;
    const int half = l >> 5;
    const int c0 = j + half * 32;        // i (lower) / f (upper)
    const int c1 = j + 64 + half * 32;   // g (lower) / o (upper)
    const float sc1 = half ? S1f : S2f;

    float e[EMBD];
#pragma unroll
    for (int k = 0; k < EMBD; ++k) e[k] = emb[v * EMBD + k];
    float z0 = bias[c0];
    float z1 = bias[c1];
#pragma unroll
    for (int k = 0; k < EMBD; ++k) {
        z0 = __builtin_fmaf(e[k], W[k * GATES + c0], z0);
        z1 = __builtin_fmaf(e[k], W[k * GATES + c1], z1);
    }
    proj2[(size_t)v * 64 + l] = (v2f){ S1f * z0, sc1 * z1 };
}

// ONE row per wave. Matvec: scalar v_fma with readlane-SGPR operands, but
// the readlanes are SOFTWARE-PIPELINED one group (4) ahead of their
// consuming FMAs, with sched_barrier(0) fences pinning the order. This
// covers the VALU-writes-SGPR -> VALU-reads-SGPR RAW hazard (~5cy x32/step)
// that made the tightly-interleaved R17 (700 cyc/step) LOSE to the
// splat-mov R11 (531): each SGPR is written >=8 instructions before use.
__global__ __launch_bounds__(64, 1) void lstm_scan_kernel(
    const int* __restrict__ tokens, const float* __restrict__ rec,
    const v2f* __restrict__ proj2, float* __restrict__ out)
{
    const int b = blockIdx.x;
    const int l = threadIdx.x;
    const int j = l & 31;
    const int half = l >> 5;
    const int c0 = j + half * 32;
    const int c1 = j + 64 + half * 32;
    const float sc1 = half ? S1f : S2f;

    // Pre-scaled rec columns for this lane's two gates (64 VGPRs)
    float R0[HIDN], R1[HIDN];
#pragma unroll
    for (int k = 0; k < HIDN; ++k) {
        R0[k] = S1f * rec[k * GATES + c0];
        R1[k] = sc1 * rec[k * GATES + c1];
    }

    const int* __restrict__ trow = tokens + (size_t)b * SEQT;

    float cs = 0.0f, hval = 0.0f;   // cs = S2*c (upper half meaningful)

    v8i tokb   = *(const v8i*)(trow);
    v8i tokb_n = *(const v8i*)(trow + TB);

    v2f xz0 = proj2[(size_t)tokb[0] * 64 + l];
    v2f xz1 = proj2[(size_t)tokb[1] * 64 + l];

    for (int tb = 0; tb < NTB; ++tb) {
        const int nb = (tb + 2 < NTB) ? (tb + 2) : (NTB - 1);
        const v8i tokb_nn = *(const v8i*)(trow + nb * TB);

#pragma unroll
        for (int s = 0; s < TB; ++s) {
            const int tpre2 = (s < TB - 2) ? tokb[s + 2] : tokb_n[s - (TB - 2)];
            const v2f xz2 = proj2[(size_t)tpre2 * 64 + l];

            // z = xz + h @ rec; scalar fma, readlanes pipelined 1 group ahead
            float z00 = xz0.x, z01 = 0.f, z02 = 0.f, z03 = 0.f;
            float z10 = xz0.y, z11 = 0.f, z12 = 0.f, z13 = 0.f;

            float hs0 = RL(hval, 32 + 0);
            float hs1 = RL(hval, 32 + 1);
            float hs2 = RL(hval, 32 + 2);
            float hs3 = RL(hval, 32 + 3);
            __builtin_amdgcn_sched_barrier(0);
#pragma unroll
            for (int g = 0; g < 8; ++g) {
                const int k = g * 4;
                float n0 = hs0, n1 = hs1, n2 = hs2, n3 = hs3;
                if (g < 7) {
                    n0 = RL(hval, 32 + k + 4);
                    n1 = RL(hval, 32 + k + 5);
                    n2 = RL(hval, 32 + k + 6);
                    n3 = RL(hval, 32 + k + 7);
                }
                __builtin_amdgcn_sched_barrier(0);
                z00 = __builtin_fmaf(hs0, R0[k],     z00);
                z10 = __builtin_fmaf(hs0, R1[k],     z10);
                z01 = __builtin_fmaf(hs1, R0[k + 1], z01);
                z11 = __builtin_fmaf(hs1, R1[k + 1], z11);
                z02 = __builtin_fmaf(hs2, R0[k + 2], z02);
                z12 = __builtin_fmaf(hs2, R1[k + 2], z12);
                z03 = __builtin_fmaf(hs3, R0[k + 3], z03);
                z13 = __builtin_fmaf(hs3, R1[k + 3], z13);
                __builtin_amdgcn_sched_barrier(0);
                hs0 = n0; hs1 = n1; hs2 = n2; hs3 = n3;
            }
            const float z0 = (z00 + z01) + (z02 + z03);
            const float z1 = (z10 + z11) + (z12 + z13);

            // activations (shared stream, per-half meaning)
            const float u = __builtin_amdgcn_rcpf(1.0f + __builtin_amdgcn_exp2f(z0)); // ig/fg
            const float w = __builtin_amdgcn_rcpf(1.0f + __builtin_amdgcn_exp2f(z1)); // gg'/og
            const float p = u * __builtin_fmaf(2.0f * S2f, w, -S2f);  // S2*ig*gg
            const v2i pr = __builtin_amdgcn_permlane32_swap(
                __float_as_int(p), __float_as_int(p), false, false);
            const float ps = __int_as_float(pr[0]);
            const float cns = __builtin_fmaf(u, cs, ps);              // S2*c_new
            const float rc = __builtin_amdgcn_rcpf(1.0f + __builtin_amdgcn_exp2f(cns));
            const float hn = w * __builtin_fmaf(2.0f, rc, -1.0f);     // og*tanh(cn)

            const bool m = (tokb[s] != 0);   // wave-uniform
            cs   = m ? cns : cs;
            hval = m ? hn : hval;

            xz0 = xz1; xz1 = xz2;
        }

        tokb = tokb_n;
        tokb_n = tokb_nn;
    }

    if (half) out[(size_t)b * HIDN + j] = hval;
}

extern "C" void kernel_launch(void* const* d_in, const int* in_sizes, int n_in,
                              void* d_out, int out_size, void* d_ws, size_t ws_size,
                              hipStream_t stream)
{
    const int*   tokens = (const int*)d_in[0];
    const float* emb    = (const float*)d_in[1];
    const float* W      = (const float*)d_in[2];
    const float* rec    = (const float*)d_in[3];
    const float* bias   = (const float*)d_in[4];
    float* out = (float*)d_out;
    v2f* proj2 = (v2f*)d_ws;   // VOCABN*64 v2f = 2.56 MB

    hipLaunchKernelGGL(build_proj_kernel, dim3(VOCABN), dim3(64), 0, stream,
                       emb, W, bias, proj2);
    hipLaunchKernelGGL(lstm_scan_kernel, dim3(BATCH), dim3(64), 0, stream,
                       tokens, rec, proj2, out);
}

// Round 27
// 531.544 us; speedup vs baseline: 1.5256x; 1.0169x over previous
//
#include <hip/hip_runtime.h>

typedef float v2f __attribute__((ext_vector_type(2)));
typedef int   v2i __attribute__((ext_vector_type(2)));
typedef int   v8i __attribute__((ext_vector_type(8)));

#define VOCABN 5000
#define EMBD   16
#define HIDN   32
#define GATES  128   // 4*HID
#define BATCH  512
#define SEQT   2048
#define TB     8      // token batch (one s_load_dwordx8)
#define NTB    (SEQT / TB)

// Gate pre-scales folded into proj table and rec columns:
//   sigmoid(z) = 1/(1+exp2(S1*z)),  S1 = -log2(e)
//   tanh(z)    = 2/(1+exp2(S2*z))-1, S2 = -2*log2(e)
#define S1f (-1.4426950408889634f)
#define S2f (-2.8853900817779268f)

// Gate-split proj table, one v2f per (token, lane):
//   lane l<32  (j=l):    { S1*z_i[j], S2*z_g[j] }
//   lane l>=32 (j=l-32): { S1*z_f[j], S1*z_o[j] }
__global__ __launch_bounds__(64, 1) void build_proj_kernel(
    const float* __restrict__ emb, const float* __restrict__ W,
    const float* __restrict__ bias, v2f* __restrict__ proj2)
{
    const int v = blockIdx.x;
    const int l = threadIdx.x;
    const int j = l & 31;
    const int half = l >> 5;
    const int c0 = j + half * 32;        // i (lower) / f (upper)
    const int c1 = j + 64 + half * 32;   // g (lower) / o (upper)
    const float sc1 = half ? S1f : S2f;

    float e[EMBD];
#pragma unroll
    for (int k = 0; k < EMBD; ++k) e[k] = emb[v * EMBD + k];
    float z0 = bias[c0];
    float z1 = bias[c1];
#pragma unroll
    for (int k = 0; k < EMBD; ++k) {
        z0 = __builtin_fmaf(e[k], W[k * GATES + c0], z0);
        z1 = __builtin_fmaf(e[k], W[k * GATES + c1], z1);
    }
    proj2[(size_t)v * 64 + l] = (v2f){ S1f * z0, sc1 * z1 };
}

// ONE row per wave (512 waves — R12/R15's 2-row packaging halved wave count
// and lost). h-broadcast through LDS: 1 ds_write + 16 broadcast ds_read_b64
// of {h[2p],h[2p+1]} pairs at wave-uniform addresses, feeding v_pk_fma over
// k-pairs against pair-packed rec columns. ~80 instrs/step vs R11's ~190
// (no readlanes, no splat movs, no SGPR hazards). Same-wave DS ordering
// guarantees the reads see the write; the 16 reads pipeline on the DS pipe
// (~50-100cy exposed), paid once per step.
__global__ __launch_bounds__(64, 1) void lstm_scan_kernel(
    const int* __restrict__ tokens, const float* __restrict__ rec,
    const v2f* __restrict__ proj2, float* __restrict__ out)
{
    const int b = blockIdx.x;
    const int l = threadIdx.x;
    const int j = l & 31;
    const int half = l >> 5;
    const int c0 = j + half * 32;
    const int c1 = j + 64 + half * 32;
    const float sc1 = half ? S1f : S2f;

    // rec columns pair-packed over k: Rc0[p] = {R[2p][c0], R[2p+1][c0]}
    v2f Rc0[16], Rc1[16];
#pragma unroll
    for (int p = 0; p < 16; ++p) {
        Rc0[p] = (v2f){ S1f * rec[(2 * p) * GATES + c0], S1f * rec[(2 * p + 1) * GATES + c0] };
        Rc1[p] = (v2f){ sc1 * rec[(2 * p) * GATES + c1], sc1 * rec[(2 * p + 1) * GATES + c1] };
    }

    __shared__ float hs[64];
    hs[l] = 0.0f;

    const int* __restrict__ trow = tokens + (size_t)b * SEQT;
    // broadcast-read pointer: wave-uniform address into the upper half
    const v2f* __restrict__ hp = (const v2f*)(&hs[32]);

    float cs = 0.0f, hval = 0.0f;   // cs = S2*c (upper half meaningful)

    v8i tokb   = *(const v8i*)(trow);
    v8i tokb_n = *(const v8i*)(trow + TB);

    v2f xz0 = proj2[(size_t)tokb[0] * 64 + l];
    v2f xz1 = proj2[(size_t)tokb[1] * 64 + l];

    for (int tb = 0; tb < NTB; ++tb) {
        const int nb = (tb + 2 < NTB) ? (tb + 2) : (NTB - 1);
        const v8i tokb_nn = *(const v8i*)(trow + nb * TB);

#pragma unroll
        for (int s = 0; s < TB; ++s) {
            const int tpre2 = (s < TB - 2) ? tokb[s + 2] : tokb_n[s - (TB - 2)];
            const v2f xz2 = proj2[(size_t)tpre2 * 64 + l];

            // publish h_{t-1} (computed at end of previous step), then
            // broadcast-read the 16 k-pairs; reads pipeline behind the write
            hs[l] = hval;
            v2f hr[16];
#pragma unroll
            for (int p = 0; p < 16; ++p) hr[p] = hp[p];

            // z = xz + h @ rec: 32 pk_fma over k-pairs, 4 split accs/column
            v2f az0 = (v2f){ xz0.x, 0.f }, az1 = (v2f){0.f, 0.f};
            v2f az2 = (v2f){0.f, 0.f},     az3 = (v2f){0.f, 0.f};
            v2f ag0 = (v2f){ xz0.y, 0.f }, ag1 = (v2f){0.f, 0.f};
            v2f ag2 = (v2f){0.f, 0.f},     ag3 = (v2f){0.f, 0.f};
#pragma unroll
            for (int p = 0; p < 16; p += 4) {
                az0 = __builtin_elementwise_fma(hr[p],     Rc0[p],     az0);
                ag0 = __builtin_elementwise_fma(hr[p],     Rc1[p],     ag0);
                az1 = __builtin_elementwise_fma(hr[p + 1], Rc0[p + 1], az1);
                ag1 = __builtin_elementwise_fma(hr[p + 1], Rc1[p + 1], ag1);
                az2 = __builtin_elementwise_fma(hr[p + 2], Rc0[p + 2], az2);
                ag2 = __builtin_elementwise_fma(hr[p + 2], Rc1[p + 2], ag2);
                az3 = __builtin_elementwise_fma(hr[p + 3], Rc0[p + 3], az3);
                ag3 = __builtin_elementwise_fma(hr[p + 3], Rc1[p + 3], ag3);
            }
            const v2f azs = (az0 + az1) + (az2 + az3);
            const v2f ags = (ag0 + ag1) + (ag2 + ag3);
            const float z0 = azs.x + azs.y;
            const float z1 = ags.x + ags.y;

            // activations (shared stream, per-half meaning)
            const float u = __builtin_amdgcn_rcpf(1.0f + __builtin_amdgcn_exp2f(z0)); // ig/fg
            const float w = __builtin_amdgcn_rcpf(1.0f + __builtin_amdgcn_exp2f(z1)); // gg'/og
            const float p = u * __builtin_fmaf(2.0f * S2f, w, -S2f);  // S2*ig*gg
            const v2i pr = __builtin_amdgcn_permlane32_swap(
                __float_as_int(p), __float_as_int(p), false, false);
            const float ps = __int_as_float(pr[0]);
            const float cns = __builtin_fmaf(u, cs, ps);              // S2*c_new
            const float rc = __builtin_amdgcn_rcpf(1.0f + __builtin_amdgcn_exp2f(cns));
            const float hn = w * __builtin_fmaf(2.0f, rc, -1.0f);     // og*tanh(cn)

            const bool m = (tokb[s] != 0);   // wave-uniform
            cs   = m ? cns : cs;
            hval = m ? hn : hval;

            xz0 = xz1; xz1 = xz2;
        }

        tokb = tokb_n;
        tokb_n = tokb_nn;
    }

    if (half) out[(size_t)b * HIDN + j] = hval;
}

extern "C" void kernel_launch(void* const* d_in, const int* in_sizes, int n_in,
                              void* d_out, int out_size, void* d_ws, size_t ws_size,
                              hipStream_t stream)
{
    const int*   tokens = (const int*)d_in[0];
    const float* emb    = (const float*)d_in[1];
    const float* W      = (const float*)d_in[2];
    const float* rec    = (const float*)d_in[3];
    const float* bias   = (const float*)d_in[4];
    float* out = (float*)d_out;
    v2f* proj2 = (v2f*)d_ws;   // VOCABN*64 v2f = 2.56 MB

    hipLaunchKernelGGL(build_proj_kernel, dim3(VOCABN), dim3(64), 0, stream,
                       emb, W, bias, proj2);
    hipLaunchKernelGGL(lstm_scan_kernel, dim3(BATCH), dim3(64), 0, stream,
                       tokens, rec, proj2, out);
}

// Round 28
// 455.561 us; speedup vs baseline: 1.7801x; 1.1668x over previous
//
#include <hip/hip_runtime.h>

typedef float v2f __attribute__((ext_vector_type(2)));
typedef int   v2i __attribute__((ext_vector_type(2)));
typedef int   v8i __attribute__((ext_vector_type(8)));
typedef unsigned long long u64;

#define VOCABN 5000
#define EMBD   16
#define HIDN   32
#define GATES  128   // 4*HID
#define BATCH  512
#define SEQT   2048
#define TB     8      // token batch (one s_load_dwordx8)
#define NTB    (SEQT / TB)

// Gate pre-scales folded into proj table and rec columns:
//   sigmoid(z) = 1/(1+exp2(S1*z)),  S1 = -log2(e)
//   tanh(z)    = 2/(1+exp2(S2*z))-1, S2 = -2*log2(e)
#define S1f (-1.4426950408889634f)
#define S2f (-2.8853900817779268f)

__device__ __forceinline__ u64 pack2(float lo, float hi) {
    return ((u64)__float_as_uint(hi) << 32) | (u64)__float_as_uint(lo);
}
__device__ __forceinline__ float lo32(u64 x) { return __uint_as_float((unsigned)x); }
__device__ __forceinline__ float hi32(u64 x) { return __uint_as_float((unsigned)(x >> 32)); }

// Gate-split proj table, one v2f per (token, lane):
//   lane l<32  (j=l):    { S1*z_i[j], S2*z_g[j] }
//   lane l>=32 (j=l-32): { S1*z_f[j], S1*z_o[j] }
__global__ __launch_bounds__(64, 1) void build_proj_kernel(
    const float* __restrict__ emb, const float* __restrict__ W,
    const float* __restrict__ bias, v2f* __restrict__ proj2)
{
    const int v = blockIdx.x;
    const int l = threadIdx.x;
    const int j = l & 31;
    const int half = l >> 5;
    const int c0 = j + half * 32;        // i (lower) / f (upper)
    const int c1 = j + 64 + half * 32;   // g (lower) / o (upper)
    const float sc1 = half ? S1f : S2f;

    float e[EMBD];
#pragma unroll
    for (int k = 0; k < EMBD; ++k) e[k] = emb[v * EMBD + k];
    float z0 = bias[c0];
    float z1 = bias[c1];
#pragma unroll
    for (int k = 0; k < EMBD; ++k) {
        z0 = __builtin_fmaf(e[k], W[k * GATES + c0], z0);
        z1 = __builtin_fmaf(e[k], W[k * GATES + c1], z1);
    }
    proj2[(size_t)v * 64 + l] = (v2f){ S1f * z0, sc1 * z1 };
}

// ONE row per wave (R11 skeleton — best measured 453us). Matvec via inline
// asm: v_readlane pairs into hardcoded even-aligned SGPR pairs s[20+2p], then
// v_pk_fma_f32 with the SGPR PAIR as the scalar operand — {h[2p],h[2p+1]}
// consumed directly, zero splat movs (R11 paid ~64/step) and zero DS ops
// (R19's LDS broadcast paid ~250cy latency). Each block issues all 16
// readlanes before the 16 pk_fmas: every SGPR is written >=15 instructions
// before its consumer, covering the VALU-writes-SGPR->VALU-reads hazard that
// sank the back-to-back R17 version. Matvec = 64 VALU instrs vs R11's ~128.
__global__ __launch_bounds__(64, 1) void lstm_scan_kernel(
    const int* __restrict__ tokens, const float* __restrict__ rec,
    const v2f* __restrict__ proj2, float* __restrict__ out)
{
    const int b = blockIdx.x;
    const int l = threadIdx.x;
    const int j = l & 31;
    const int half = l >> 5;
    const int c0 = j + half * 32;
    const int c1 = j + 64 + half * 32;
    const float sc1 = half ? S1f : S2f;

    // rec columns pair-packed over k as u64 {R[2p][c], R[2p+1][c]} (64 VGPRs)
    u64 rc0q[16], rc1q[16];
#pragma unroll
    for (int p = 0; p < 16; ++p) {
        rc0q[p] = pack2(S1f * rec[(2 * p) * GATES + c0], S1f * rec[(2 * p + 1) * GATES + c0]);
        rc1q[p] = pack2(sc1 * rec[(2 * p) * GATES + c1], sc1 * rec[(2 * p + 1) * GATES + c1]);
    }

    const int* __restrict__ trow = tokens + (size_t)b * SEQT;

    float cs = 0.0f, hval = 0.0f;   // cs = S2*c (upper half meaningful)

    v8i tokb   = *(const v8i*)(trow);
    v8i tokb_n = *(const v8i*)(trow + TB);

    v2f xz0 = proj2[(size_t)tokb[0] * 64 + l];
    v2f xz1 = proj2[(size_t)tokb[1] * 64 + l];

    for (int tb = 0; tb < NTB; ++tb) {
        const int nb = (tb + 2 < NTB) ? (tb + 2) : (NTB - 1);
        const v8i tokb_nn = *(const v8i*)(trow + nb * TB);

#pragma unroll
        for (int s = 0; s < TB; ++s) {
            const int tpre2 = (s < TB - 2) ? tokb[s + 2] : tokb_n[s - (TB - 2)];
            const v2f xz2 = proj2[(size_t)tpre2 * 64 + l];

            // z = xz + h @ rec ; accumulators as u64 (VGPR pairs), 2/column
            u64 a0 = (u64)__float_as_uint(xz0.x);
            u64 a1 = 0ull;
            u64 g0 = (u64)__float_as_uint(xz0.y);
            u64 g1 = 0ull;
            const int hvi = __float_as_int(hval);

            // k = 0..15 (h lanes 32..47)
            asm volatile(
                "v_readlane_b32 s20, %4, 32\n\t"
                "v_readlane_b32 s21, %4, 33\n\t"
                "v_readlane_b32 s22, %4, 34\n\t"
                "v_readlane_b32 s23, %4, 35\n\t"
                "v_readlane_b32 s24, %4, 36\n\t"
                "v_readlane_b32 s25, %4, 37\n\t"
                "v_readlane_b32 s26, %4, 38\n\t"
                "v_readlane_b32 s27, %4, 39\n\t"
                "v_readlane_b32 s28, %4, 40\n\t"
                "v_readlane_b32 s29, %4, 41\n\t"
                "v_readlane_b32 s30, %4, 42\n\t"
                "v_readlane_b32 s31, %4, 43\n\t"
                "v_readlane_b32 s32, %4, 44\n\t"
                "v_readlane_b32 s33, %4, 45\n\t"
                "v_readlane_b32 s34, %4, 46\n\t"
                "v_readlane_b32 s35, %4, 47\n\t"
                "v_pk_fma_f32 %0, s[20:21], %5, %0\n\t"
                "v_pk_fma_f32 %2, s[20:21], %13, %2\n\t"
                "v_pk_fma_f32 %1, s[22:23], %6, %1\n\t"
                "v_pk_fma_f32 %3, s[22:23], %14, %3\n\t"
                "v_pk_fma_f32 %0, s[24:25], %7, %0\n\t"
                "v_pk_fma_f32 %2, s[24:25], %15, %2\n\t"
                "v_pk_fma_f32 %1, s[26:27], %8, %1\n\t"
                "v_pk_fma_f32 %3, s[26:27], %16, %3\n\t"
                "v_pk_fma_f32 %0, s[28:29], %9, %0\n\t"
                "v_pk_fma_f32 %2, s[28:29], %17, %2\n\t"
                "v_pk_fma_f32 %1, s[30:31], %10, %1\n\t"
                "v_pk_fma_f32 %3, s[30:31], %18, %3\n\t"
                "v_pk_fma_f32 %0, s[32:33], %11, %0\n\t"
                "v_pk_fma_f32 %2, s[32:33], %19, %2\n\t"
                "v_pk_fma_f32 %1, s[34:35], %12, %1\n\t"
                "v_pk_fma_f32 %3, s[34:35], %20, %3"
                : "+v"(a0), "+v"(a1), "+v"(g0), "+v"(g1)
                : "v"(hvi),
                  "v"(rc0q[0]), "v"(rc0q[1]), "v"(rc0q[2]), "v"(rc0q[3]),
                  "v"(rc0q[4]), "v"(rc0q[5]), "v"(rc0q[6]), "v"(rc0q[7]),
                  "v"(rc1q[0]), "v"(rc1q[1]), "v"(rc1q[2]), "v"(rc1q[3]),
                  "v"(rc1q[4]), "v"(rc1q[5]), "v"(rc1q[6]), "v"(rc1q[7])
                : "s20","s21","s22","s23","s24","s25","s26","s27",
                  "s28","s29","s30","s31","s32","s33","s34","s35");

            // k = 16..31 (h lanes 48..63)
            asm volatile(
                "v_readlane_b32 s20, %4, 48\n\t"
                "v_readlane_b32 s21, %4, 49\n\t"
                "v_readlane_b32 s22, %4, 50\n\t"
                "v_readlane_b32 s23, %4, 51\n\t"
                "v_readlane_b32 s24, %4, 52\n\t"
                "v_readlane_b32 s25, %4, 53\n\t"
                "v_readlane_b32 s26, %4, 54\n\t"
                "v_readlane_b32 s27, %4, 55\n\t"
                "v_readlane_b32 s28, %4, 56\n\t"
                "v_readlane_b32 s29, %4, 57\n\t"
                "v_readlane_b32 s30, %4, 58\n\t"
                "v_readlane_b32 s31, %4, 59\n\t"
                "v_readlane_b32 s32, %4, 60\n\t"
                "v_readlane_b32 s33, %4, 61\n\t"
                "v_readlane_b32 s34, %4, 62\n\t"
                "v_readlane_b32 s35, %4, 63\n\t"
                "v_pk_fma_f32 %0, s[20:21], %5, %0\n\t"
                "v_pk_fma_f32 %2, s[20:21], %13, %2\n\t"
                "v_pk_fma_f32 %1, s[22:23], %6, %1\n\t"
                "v_pk_fma_f32 %3, s[22:23], %14, %3\n\t"
                "v_pk_fma_f32 %0, s[24:25], %7, %0\n\t"
                "v_pk_fma_f32 %2, s[24:25], %15, %2\n\t"
                "v_pk_fma_f32 %1, s[26:27], %8, %1\n\t"
                "v_pk_fma_f32 %3, s[26:27], %16, %3\n\t"
                "v_pk_fma_f32 %0, s[28:29], %9, %0\n\t"
                "v_pk_fma_f32 %2, s[28:29], %17, %2\n\t"
                "v_pk_fma_f32 %1, s[30:31], %10, %1\n\t"
                "v_pk_fma_f32 %3, s[30:31], %18, %3\n\t"
                "v_pk_fma_f32 %0, s[32:33], %11, %0\n\t"
                "v_pk_fma_f32 %2, s[32:33], %19, %2\n\t"
                "v_pk_fma_f32 %1, s[34:35], %12, %1\n\t"
                "v_pk_fma_f32 %3, s[34:35], %20, %3"
                : "+v"(a0), "+v"(a1), "+v"(g0), "+v"(g1)
                : "v"(hvi),
                  "v"(rc0q[8]),  "v"(rc0q[9]),  "v"(rc0q[10]), "v"(rc0q[11]),
                  "v"(rc0q[12]), "v"(rc0q[13]), "v"(rc0q[14]), "v"(rc0q[15]),
                  "v"(rc1q[8]),  "v"(rc1q[9]),  "v"(rc1q[10]), "v"(rc1q[11]),
                  "v"(rc1q[12]), "v"(rc1q[13]), "v"(rc1q[14]), "v"(rc1q[15])
                : "s20","s21","s22","s23","s24","s25","s26","s27",
                  "s28","s29","s30","s31","s32","s33","s34","s35");

            const float z0 = (lo32(a0) + hi32(a0)) + (lo32(a1) + hi32(a1));
            const float z1 = (lo32(g0) + hi32(g0)) + (lo32(g1) + hi32(g1));

            // activations (shared stream, per-half meaning)
            const float u = __builtin_amdgcn_rcpf(1.0f + __builtin_amdgcn_exp2f(z0)); // ig/fg
            const float w = __builtin_amdgcn_rcpf(1.0f + __builtin_amdgcn_exp2f(z1)); // gg'/og
            const float p = u * __builtin_fmaf(2.0f * S2f, w, -S2f);  // S2*ig*gg
            const v2i pr = __builtin_amdgcn_permlane32_swap(
                __float_as_int(p), __float_as_int(p), false, false);
            const float ps = __int_as_float(pr[0]);
            const float cns = __builtin_fmaf(u, cs, ps);              // S2*c_new
            const float rc = __builtin_amdgcn_rcpf(1.0f + __builtin_amdgcn_exp2f(cns));
            const float hn = w * __builtin_fmaf(2.0f, rc, -1.0f);     // og*tanh(cn)

            const bool m = (tokb[s] != 0);   // wave-uniform
            cs   = m ? cns : cs;
            hval = m ? hn : hval;

            xz0 = xz1; xz1 = xz2;
        }

        tokb = tokb_n;
        tokb_n = tokb_nn;
    }

    if (half) out[(size_t)b * HIDN + j] = hval;
}

extern "C" void kernel_launch(void* const* d_in, const int* in_sizes, int n_in,
                              void* d_out, int out_size, void* d_ws, size_t ws_size,
                              hipStream_t stream)
{
    const int*   tokens = (const int*)d_in[0];
    const float* emb    = (const float*)d_in[1];
    const float* W      = (const float*)d_in[2];
    const float* rec    = (const float*)d_in[3];
    const float* bias   = (const float*)d_in[4];
    float* out = (float*)d_out;
    v2f* proj2 = (v2f*)d_ws;   // VOCABN*64 v2f = 2.56 MB

    hipLaunchKernelGGL(build_proj_kernel, dim3(VOCABN), dim3(64), 0, stream,
                       emb, W, bias, proj2);
    hipLaunchKernelGGL(lstm_scan_kernel, dim3(BATCH), dim3(64), 0, stream,
                       tokens, rec, proj2, out);
}